// Round 1
// baseline (315.846 us; speedup 1.0000x reference)
//
#include <hip/hip_runtime.h>

// Fused causal MHA: B=2, N=2048, D=1024, H=16, dh=64, scale=0.125
// Pipeline: cast x -> bf16 | transpose-cast weights | GEMM1 (qkv) |
//           transpose V | flash attention | GEMM3 (out proj, f32 out)
// All matmuls: mfma_f32_16x16x32_bf16, f32 accumulate.

typedef __bf16 bf16x8 __attribute__((ext_vector_type(8)));
typedef float f32x4 __attribute__((ext_vector_type(4)));

#define MFMA16(a, b, c) __builtin_amdgcn_mfma_f32_16x16x32_bf16((a), (b), (c), 0, 0, 0)

__device__ __forceinline__ unsigned short f2bf(float f) {
  unsigned int u = __float_as_uint(f);
  u += 0x7fffu + ((u >> 16) & 1u);   // round-to-nearest-even
  return (unsigned short)(u >> 16);
}

// ---------------- elementwise cast f32 -> bf16 ------------------------------
__global__ void cast_bf16_kernel(const float* __restrict__ in,
                                 unsigned short* __restrict__ out, int n4) {
  int i = blockIdx.x * blockDim.x + threadIdx.x;
  if (i >= n4) return;
  float4 v = ((const float4*)in)[i];
  ushort4 o;
  o.x = f2bf(v.x); o.y = f2bf(v.y); o.z = f2bf(v.z); o.w = f2bf(v.w);
  ((ushort4*)out)[i] = o;
}

// ---------------- transpose + cast: f32 [R][C] -> bf16 [C][R] ---------------
__global__ void transpose_cast_kernel(const float* __restrict__ in,
                                      unsigned short* __restrict__ out,
                                      int R, int C) {
  __shared__ float tile[32][33];
  const int bx = blockIdx.x, by = blockIdx.y;
  const int tx = threadIdx.x, ty = threadIdx.y;
#pragma unroll
  for (int i = ty; i < 32; i += 8)
    tile[i][tx] = in[(size_t)(by * 32 + i) * C + bx * 32 + tx];
  __syncthreads();
#pragma unroll
  for (int i = ty; i < 32; i += 8)
    out[(size_t)(bx * 32 + i) * R + by * 32 + tx] = f2bf(tile[tx][i]);
}

// ------- transpose V region of qkv (bf16) into vT[b][h*64+dim][n] -----------
__global__ void transpose_v_kernel(const unsigned short* __restrict__ qkv,
                                   unsigned short* __restrict__ vT) {
  __shared__ unsigned short tile[32][33];
  const int b = blockIdx.z, bx = blockIdx.x, by = blockIdx.y;
  const int tx = threadIdx.x, ty = threadIdx.y;
#pragma unroll
  for (int i = ty; i < 32; i += 8)
    tile[i][tx] = qkv[(size_t)(b * 2048 + by * 32 + i) * 3072 + 2048 + bx * 32 + tx];
  __syncthreads();
#pragma unroll
  for (int i = ty; i < 32; i += 8)
    vT[((size_t)b * 1024 + bx * 32 + i) * 2048 + by * 32 + tx] = tile[tx][i];
}

// ---------------- 128x128 bf16 GEMM: C = A[M][K] * BT[Nc][K]^T --------------
// m97 structure: BK=32, global_load_lds width 16, 4 waves -> 64x64 each,
// 16 MFMA + 8 ds_read_b128 per K-step, 2 barriers per K-step.
template <int OUT_BF16>
__global__ __launch_bounds__(256) void gemm128_kernel(
    const unsigned short* __restrict__ A,   // [M][K] bf16
    const unsigned short* __restrict__ BT,  // [Nc][K] bf16 (i.e. B transposed)
    void* __restrict__ Cp, int M, int Nc, int K) {
  __shared__ unsigned short lA[128 * 32];
  __shared__ unsigned short lB[128 * 32];
  const int t = threadIdx.x;
  const int l = t & 63, g = l >> 4, c = l & 15;
  const int w = t >> 6;
  const int wm = (w >> 1) * 64, wn = (w & 1) * 64;
  const int bm = blockIdx.y * 128, bn = blockIdx.x * 128;

  // staging: idx = round*256 + t; row = idx/4 (of 128), colchunk = idx%4 (8 elems)
  const int i0 = t, i1 = 256 + t;
  const unsigned short* ga0 = A + (size_t)(bm + (i0 >> 2)) * K + (i0 & 3) * 8;
  const unsigned short* ga1 = A + (size_t)(bm + (i1 >> 2)) * K + (i1 & 3) * 8;
  const unsigned short* gb0 = BT + (size_t)(bn + (i0 >> 2)) * K + (i0 & 3) * 8;
  const unsigned short* gb1 = BT + (size_t)(bn + (i1 >> 2)) * K + (i1 & 3) * 8;
  // wave-uniform LDS bases (HW adds lane*16B)
  unsigned short* la0 = lA + (i0 & ~63) * 8;
  unsigned short* la1 = lA + (i1 & ~63) * 8;
  unsigned short* lb0 = lB + (i0 & ~63) * 8;
  unsigned short* lb1 = lB + (i1 & ~63) * 8;

  f32x4 acc[4][4] = {};

  for (int kk = 0; kk < K; kk += 32) {
    __syncthreads();  // previous compute done before overwrite
    __builtin_amdgcn_global_load_lds(
        (const __attribute__((address_space(1))) void*)(ga0 + kk),
        (__attribute__((address_space(3))) void*)la0, 16, 0, 0);
    __builtin_amdgcn_global_load_lds(
        (const __attribute__((address_space(1))) void*)(ga1 + kk),
        (__attribute__((address_space(3))) void*)la1, 16, 0, 0);
    __builtin_amdgcn_global_load_lds(
        (const __attribute__((address_space(1))) void*)(gb0 + kk),
        (__attribute__((address_space(3))) void*)lb0, 16, 0, 0);
    __builtin_amdgcn_global_load_lds(
        (const __attribute__((address_space(1))) void*)(gb1 + kk),
        (__attribute__((address_space(3))) void*)lb1, 16, 0, 0);
    __syncthreads();  // compiler drains vmcnt before barrier -> tiles ready

    bf16x8 af[4], bfr[4];
#pragma unroll
    for (int mi = 0; mi < 4; ++mi)
      af[mi] = *(const bf16x8*)(lA + (wm + mi * 16 + c) * 32 + g * 8);
#pragma unroll
    for (int ni = 0; ni < 4; ++ni)
      bfr[ni] = *(const bf16x8*)(lB + (wn + ni * 16 + c) * 32 + g * 8);
#pragma unroll
    for (int mi = 0; mi < 4; ++mi)
#pragma unroll
      for (int ni = 0; ni < 4; ++ni)
        acc[mi][ni] = MFMA16(af[mi], bfr[ni], acc[mi][ni]);
  }

  // epilogue: D row = (l>>4)*4 + r, col = l&15
  if (OUT_BF16) {
    unsigned short* Cc = (unsigned short*)Cp;
#pragma unroll
    for (int mi = 0; mi < 4; ++mi)
#pragma unroll
      for (int r = 0; r < 4; ++r) {
        const int gr = bm + wm + mi * 16 + g * 4 + r;
#pragma unroll
        for (int ni = 0; ni < 4; ++ni)
          Cc[(size_t)gr * Nc + bn + wn + ni * 16 + c] = f2bf(acc[mi][ni][r]);
      }
  } else {
    float* Cf = (float*)Cp;
#pragma unroll
    for (int mi = 0; mi < 4; ++mi)
#pragma unroll
      for (int r = 0; r < 4; ++r) {
        const int gr = bm + wm + mi * 16 + g * 4 + r;
#pragma unroll
        for (int ni = 0; ni < 4; ++ni)
          Cf[(size_t)gr * Nc + bn + wn + ni * 16 + c] = acc[mi][ni][r];
      }
  }
}

// ---------------- flash attention (causal, online softmax) ------------------
// grid: (32 q-blocks of 64, 32 b*h). 4 waves/block, 16 q-rows per wave.
// KV-block = 32. All LDS traffic is intra-wave (P bounce) -> no barriers in
// the K-loop (waves have different causal trip counts!).
__global__ __launch_bounds__(256) void attn_kernel(
    const unsigned short* __restrict__ qkv,  // [4096][3072] bf16 (Q|K|V)
    const unsigned short* __restrict__ vT,   // [2][1024][2048] bf16
    unsigned short* __restrict__ aout) {     // [4096][1024] bf16
  const int t = threadIdx.x, w = t >> 6, l = t & 63, g = l >> 4, c = l & 15;
  const int bh = blockIdx.y, b = bh >> 4, h = bh & 15;
  const int q0 = blockIdx.x * 64 + w * 16;

  __shared__ __align__(16) unsigned short pl[4][16][40];  // per-wave P tile

  const unsigned short* Qbase = qkv + (size_t)b * 2048 * 3072 + h * 64;
  const unsigned short* Kbase = Qbase + 1024;
  const unsigned short* Vb = vT + ((size_t)b * 1024 + h * 64) * 2048;

  // Q fragments (A-frag: row = l&15, k = f*32 + g*8 + j), held all kernel
  bf16x8 aq0 = *(const bf16x8*)(Qbase + (size_t)(q0 + c) * 3072 + g * 8);
  bf16x8 aq1 = *(const bf16x8*)(Qbase + (size_t)(q0 + c) * 3072 + 32 + g * 8);

  f32x4 o[4] = {};
  float m[4], ll[4];
#pragma unroll
  for (int r = 0; r < 4; ++r) { m[r] = -__builtin_inff(); ll[r] = 0.f; }

  const int jbmax = (q0 + 15) >> 5;
  for (int jb = 0; jb <= jbmax; ++jb) {
    const int kb = jb * 32;
    // K fragments (B-frag: col = kv = nt*16 + (l&15), k = f*32 + g*8 + j)
    bf16x8 k00 = *(const bf16x8*)(Kbase + (size_t)(kb + c) * 3072 + g * 8);
    bf16x8 k01 = *(const bf16x8*)(Kbase + (size_t)(kb + c) * 3072 + 32 + g * 8);
    bf16x8 k10 = *(const bf16x8*)(Kbase + (size_t)(kb + 16 + c) * 3072 + g * 8);
    bf16x8 k11 = *(const bf16x8*)(Kbase + (size_t)(kb + 16 + c) * 3072 + 32 + g * 8);
    f32x4 s0 = {}, s1 = {};
    s0 = MFMA16(aq0, k00, s0);
    s0 = MFMA16(aq1, k01, s0);
    s1 = MFMA16(aq0, k10, s1);
    s1 = MFMA16(aq1, k11, s1);

#pragma unroll
    for (int r = 0; r < 4; ++r) {
      const int qa = q0 + g * 4 + r;  // this lane's q row (D layout)
      float v0 = (kb + c <= qa) ? s0[r] * 0.125f : -__builtin_inff();
      float v1 = (kb + 16 + c <= qa) ? s1[r] * 0.125f : -__builtin_inff();
      float rm = fmaxf(v0, v1);
      rm = fmaxf(rm, __shfl_xor(rm, 1));
      rm = fmaxf(rm, __shfl_xor(rm, 2));
      rm = fmaxf(rm, __shfl_xor(rm, 4));
      rm = fmaxf(rm, __shfl_xor(rm, 8));
      const float mn = fmaxf(m[r], rm);       // finite after block 0
      const float al = __expf(m[r] - mn);
      const float p0 = __expf(v0 - mn);       // masked -> exp(-inf) = 0
      const float p1 = __expf(v1 - mn);
      m[r] = mn;
      float rs = p0 + p1;
      rs += __shfl_xor(rs, 1);
      rs += __shfl_xor(rs, 2);
      rs += __shfl_xor(rs, 4);
      rs += __shfl_xor(rs, 8);
      ll[r] = ll[r] * al + rs;
#pragma unroll
      for (int dt = 0; dt < 4; ++dt) o[dt][r] *= al;
      // D layout -> LDS (row = g*4+r, cols c and 16+c)
      pl[w][g * 4 + r][c] = f2bf(p0);
      pl[w][g * 4 + r][16 + c] = f2bf(p1);
    }
    // P as A-frag: row = l&15, k = g*8 + j (intra-wave LDS, in-order DS pipe)
    bf16x8 pa = *(const bf16x8*)(&pl[w][c][g * 8]);
#pragma unroll
    for (int dt = 0; dt < 4; ++dt) {
      // V B-frag from vT: col = dim = dt*16 + (l&15), k = kv = g*8 + j
      bf16x8 bv = *(const bf16x8*)(Vb + (size_t)(dt * 16 + c) * 2048 + kb + g * 8);
      o[dt] = MFMA16(pa, bv, o[dt]);
    }
  }

#pragma unroll
  for (int dt = 0; dt < 4; ++dt)
#pragma unroll
    for (int r = 0; r < 4; ++r) {
      const size_t row = (size_t)(b * 2048 + q0 + g * 4 + r);
      aout[row * 1024 + h * 64 + dt * 16 + c] = f2bf(o[dt][r] / ll[r]);
    }
}

// ---------------------------------------------------------------------------
extern "C" void kernel_launch(void* const* d_in, const int* in_sizes, int n_in,
                              void* d_out, int out_size, void* d_ws, size_t ws_size,
                              hipStream_t stream) {
  const float* x = (const float*)d_in[0];      // [2,2048,1024]
  const float* wqkv = (const float*)d_in[1];   // [1024,3072]
  const float* wout = (const float*)d_in[2];   // [1024,1024]
  float* out = (float*)d_out;                  // [2,2048,1024] f32

  unsigned short* ws = (unsigned short*)d_ws;  // ~58.7 MB of bf16 scratch
  unsigned short* xb = ws;                                  // 4096*1024
  unsigned short* wqkvT = xb + (size_t)4096 * 1024;         // 3072*1024
  unsigned short* woutT = wqkvT + (size_t)3072 * 1024;      // 1024*1024
  unsigned short* qkv = woutT + (size_t)1024 * 1024;        // 4096*3072
  unsigned short* vT = qkv + (size_t)4096 * 3072;           // 2*1024*2048
  unsigned short* aout = vT + (size_t)2 * 1024 * 2048;      // 4096*1024

  cast_bf16_kernel<<<4096, 256, 0, stream>>>(x, xb, 4096 * 1024 / 4);
  transpose_cast_kernel<<<dim3(96, 32), dim3(32, 8), 0, stream>>>(wqkv, wqkvT, 1024, 3072);
  transpose_cast_kernel<<<dim3(32, 32), dim3(32, 8), 0, stream>>>(wout, woutT, 1024, 1024);
  gemm128_kernel<1><<<dim3(24, 32), 256, 0, stream>>>(xb, wqkvT, qkv, 4096, 3072, 1024);
  transpose_v_kernel<<<dim3(32, 64, 2), dim3(32, 8), 0, stream>>>(qkv, vT);
  attn_kernel<<<dim3(32, 32), 256, 0, stream>>>(qkv, vT, aout);
  gemm128_kernel<0><<<dim3(8, 32), 256, 0, stream>>>(aout, woutT, out, 4096, 1024, 1024);
}

// Round 2
// 208.839 us; speedup vs baseline: 1.5124x; 1.5124x over previous
//
#include <hip/hip_runtime.h>

// Fused causal MHA: B=2, N=2048, D=1024, H=16, dh=64
// Round 2: attention rewrite — swapped QK^T (mfma(K,Q)) for in-lane softmax,
// paired causal tiles for load balance, XCD swizzle, exp2 domain, defer-max.

typedef __bf16 bf16x8 __attribute__((ext_vector_type(8)));
typedef float f32x4 __attribute__((ext_vector_type(4)));

#define MFMA16(a, b, c) __builtin_amdgcn_mfma_f32_16x16x32_bf16((a), (b), (c), 0, 0, 0)

__device__ __forceinline__ unsigned short f2bf(float f) {
  unsigned int u = __float_as_uint(f);
  u += 0x7fffu + ((u >> 16) & 1u);   // round-to-nearest-even
  return (unsigned short)(u >> 16);
}

// ---------------- elementwise cast f32 -> bf16 ------------------------------
__global__ void cast_bf16_kernel(const float* __restrict__ in,
                                 unsigned short* __restrict__ out, int n4) {
  int i = blockIdx.x * blockDim.x + threadIdx.x;
  if (i >= n4) return;
  float4 v = ((const float4*)in)[i];
  ushort4 o;
  o.x = f2bf(v.x); o.y = f2bf(v.y); o.z = f2bf(v.z); o.w = f2bf(v.w);
  ((ushort4*)out)[i] = o;
}

// ------- transpose + cast: f32 [R][C] -> bf16 [C][R], scale first rows ------
// Rows of OUTPUT < scale_rows get multiplied by 0.125*log2(e) (Q pre-scale,
// moves softmax into exp2 domain).
__global__ void transpose_cast_kernel(const float* __restrict__ in,
                                      unsigned short* __restrict__ out,
                                      int R, int C, int scale_rows) {
  __shared__ float tile[32][33];
  const int bx = blockIdx.x, by = blockIdx.y;
  const int tx = threadIdx.x, ty = threadIdx.y;
#pragma unroll
  for (int i = ty; i < 32; i += 8)
    tile[i][tx] = in[(size_t)(by * 32 + i) * C + bx * 32 + tx];
  __syncthreads();
#pragma unroll
  for (int i = ty; i < 32; i += 8) {
    const int orow = bx * 32 + i;
    const float s = (orow < scale_rows) ? 0.18033688f : 1.0f;  // 0.125*log2e
    out[(size_t)orow * R + by * 32 + tx] = f2bf(tile[tx][i] * s);
  }
}

// ------- transpose V region of qkv (bf16) into vT[b][h*64+dim][n] -----------
__global__ void transpose_v_kernel(const unsigned short* __restrict__ qkv,
                                   unsigned short* __restrict__ vT) {
  __shared__ unsigned short tile[32][33];
  const int b = blockIdx.z, bx = blockIdx.x, by = blockIdx.y;
  const int tx = threadIdx.x, ty = threadIdx.y;
#pragma unroll
  for (int i = ty; i < 32; i += 8)
    tile[i][tx] = qkv[(size_t)(b * 2048 + by * 32 + i) * 3072 + 2048 + bx * 32 + tx];
  __syncthreads();
#pragma unroll
  for (int i = ty; i < 32; i += 8)
    vT[((size_t)b * 1024 + bx * 32 + i) * 2048 + by * 32 + tx] = tile[tx][i];
}

// ---------------- 128x128 bf16 GEMM: C = A[M][K] * BT[Nc][K]^T --------------
template <int OUT_BF16>
__global__ __launch_bounds__(256) void gemm128_kernel(
    const unsigned short* __restrict__ A,   // [M][K] bf16
    const unsigned short* __restrict__ BT,  // [Nc][K] bf16
    void* __restrict__ Cp, int M, int Nc, int K) {
  __shared__ unsigned short lA[128 * 32];
  __shared__ unsigned short lB[128 * 32];
  const int t = threadIdx.x;
  const int l = t & 63, g = l >> 4, c = l & 15;
  const int w = t >> 6;
  const int wm = (w >> 1) * 64, wn = (w & 1) * 64;
  const int bm = blockIdx.y * 128, bn = blockIdx.x * 128;

  const int i0 = t, i1 = 256 + t;
  const unsigned short* ga0 = A + (size_t)(bm + (i0 >> 2)) * K + (i0 & 3) * 8;
  const unsigned short* ga1 = A + (size_t)(bm + (i1 >> 2)) * K + (i1 & 3) * 8;
  const unsigned short* gb0 = BT + (size_t)(bn + (i0 >> 2)) * K + (i0 & 3) * 8;
  const unsigned short* gb1 = BT + (size_t)(bn + (i1 >> 2)) * K + (i1 & 3) * 8;
  unsigned short* la0 = lA + (i0 & ~63) * 8;
  unsigned short* la1 = lA + (i1 & ~63) * 8;
  unsigned short* lb0 = lB + (i0 & ~63) * 8;
  unsigned short* lb1 = lB + (i1 & ~63) * 8;

  f32x4 acc[4][4] = {};

  for (int kk = 0; kk < K; kk += 32) {
    __syncthreads();
    __builtin_amdgcn_global_load_lds(
        (const __attribute__((address_space(1))) void*)(ga0 + kk),
        (__attribute__((address_space(3))) void*)la0, 16, 0, 0);
    __builtin_amdgcn_global_load_lds(
        (const __attribute__((address_space(1))) void*)(ga1 + kk),
        (__attribute__((address_space(3))) void*)la1, 16, 0, 0);
    __builtin_amdgcn_global_load_lds(
        (const __attribute__((address_space(1))) void*)(gb0 + kk),
        (__attribute__((address_space(3))) void*)lb0, 16, 0, 0);
    __builtin_amdgcn_global_load_lds(
        (const __attribute__((address_space(1))) void*)(gb1 + kk),
        (__attribute__((address_space(3))) void*)lb1, 16, 0, 0);
    __syncthreads();

    bf16x8 af[4], bfr[4];
#pragma unroll
    for (int mi = 0; mi < 4; ++mi)
      af[mi] = *(const bf16x8*)(lA + (wm + mi * 16 + c) * 32 + g * 8);
#pragma unroll
    for (int ni = 0; ni < 4; ++ni)
      bfr[ni] = *(const bf16x8*)(lB + (wn + ni * 16 + c) * 32 + g * 8);
#pragma unroll
    for (int mi = 0; mi < 4; ++mi)
#pragma unroll
      for (int ni = 0; ni < 4; ++ni)
        acc[mi][ni] = MFMA16(af[mi], bfr[ni], acc[mi][ni]);
  }

  if (OUT_BF16) {
    unsigned short* Cc = (unsigned short*)Cp;
#pragma unroll
    for (int mi = 0; mi < 4; ++mi)
#pragma unroll
      for (int r = 0; r < 4; ++r) {
        const int gr = bm + wm + mi * 16 + g * 4 + r;
#pragma unroll
        for (int ni = 0; ni < 4; ++ni)
          Cc[(size_t)gr * Nc + bn + wn + ni * 16 + c] = f2bf(acc[mi][ni][r]);
      }
  } else {
    float* Cf = (float*)Cp;
#pragma unroll
    for (int mi = 0; mi < 4; ++mi)
#pragma unroll
      for (int r = 0; r < 4; ++r) {
        const int gr = bm + wm + mi * 16 + g * 4 + r;
#pragma unroll
        for (int ni = 0; ni < 4; ++ni)
          Cf[(size_t)gr * Nc + bn + wn + ni * 16 + c] = acc[mi][ni][r];
      }
  }
}

// ---------------- flash attention (causal, swapped QK^T) --------------------
// grid: 512 blocks (XCD-swizzled). Block handles bh = id>>4 and the balanced
// causal tile pair {31 - (id&15), id&15} (64 q-rows each; 4 waves x 16 rows).
// Swapped QK^T: S^T = mfma(K, Q) -> lane (g,c) holds S[q0+c][kb+g*4+r] for
// r=0..3 (s0: kv 0-15, s1: kv 16-31). Softmax per lane over 8 values + 2
// shfl_xor. P bounced through per-wave LDS into A-frag layout. exp2 domain
// (0.125*log2e folded into Q). Defer-max: skip O-rescale when max grows <= 5.
__global__ __launch_bounds__(256) void attn_kernel(
    const unsigned short* __restrict__ qkv,  // [4096][3072] bf16 (Q|K|V)
    const unsigned short* __restrict__ vT,   // [2][1024][2048] bf16
    unsigned short* __restrict__ aout) {     // [4096][1024] bf16
  const int t = threadIdx.x, w = t >> 6, l = t & 63, g = l >> 4, c = l & 15;
  const int g4 = g * 4;

  // XCD-bijective swizzle: 512 blocks = 8 XCDs x 64 -> 4 heads per XCD
  const int id0 = blockIdx.x;
  const int id = (id0 & 7) * 64 + (id0 >> 3);
  const int bx = id & 15, bh = id >> 4;
  const int b = bh >> 4, h = bh & 15;

  __shared__ __align__(16) unsigned short pl[4][16][40];  // per-wave P tile

  const unsigned short* Qbase = qkv + (size_t)b * 2048 * 3072 + h * 64;
  const unsigned short* Kbase = Qbase + 1024;
  const unsigned short* Vb = vT + ((size_t)b * 1024 + h * 64) * 2048;

#pragma unroll 1
  for (int pass = 0; pass < 2; ++pass) {
    const int tile = pass ? bx : (31 - bx);
    const int q0 = tile * 64 + w * 16;
    const int qc = q0 + c;

    // Q fragments (B-operand: col = q0+c, k = d)
    bf16x8 bq0 = *(const bf16x8*)(Qbase + (size_t)qc * 3072 + g * 8);
    bf16x8 bq1 = *(const bf16x8*)(Qbase + (size_t)qc * 3072 + 32 + g * 8);

    f32x4 o[4] = {};
    float m_c = -__builtin_inff(), ll_c = 0.f;

    const int jbmax = (q0 + 15) >> 5;
    // preload K frags for jb=0 (A-operand: row = kv local, k = d)
    bf16x8 nk00 = *(const bf16x8*)(Kbase + (size_t)(c) * 3072 + g * 8);
    bf16x8 nk01 = *(const bf16x8*)(Kbase + (size_t)(c) * 3072 + 32 + g * 8);
    bf16x8 nk10 = *(const bf16x8*)(Kbase + (size_t)(16 + c) * 3072 + g * 8);
    bf16x8 nk11 = *(const bf16x8*)(Kbase + (size_t)(16 + c) * 3072 + 32 + g * 8);

    for (int jb = 0; jb <= jbmax; ++jb) {
      const int kb = jb * 32;
      const bf16x8 k00 = nk00, k01 = nk01, k10 = nk10, k11 = nk11;

      // V B-frags for this block (independent -> hidden under QK+softmax)
      bf16x8 bv0 = *(const bf16x8*)(Vb + (size_t)(0 * 16 + c) * 2048 + kb + g * 8);
      bf16x8 bv1 = *(const bf16x8*)(Vb + (size_t)(1 * 16 + c) * 2048 + kb + g * 8);
      bf16x8 bv2 = *(const bf16x8*)(Vb + (size_t)(2 * 16 + c) * 2048 + kb + g * 8);
      bf16x8 bv3 = *(const bf16x8*)(Vb + (size_t)(3 * 16 + c) * 2048 + kb + g * 8);

      f32x4 s0 = {}, s1 = {};
      s0 = MFMA16(k00, bq0, s0);
      s0 = MFMA16(k01, bq1, s0);
      s1 = MFMA16(k10, bq0, s1);
      s1 = MFMA16(k11, bq1, s1);

      // prefetch K for next block (clamped address on last iter)
      const int kbn = (jb < jbmax) ? kb + 32 : 0;
      nk00 = *(const bf16x8*)(Kbase + (size_t)(kbn + c) * 3072 + g * 8);
      nk01 = *(const bf16x8*)(Kbase + (size_t)(kbn + c) * 3072 + 32 + g * 8);
      nk10 = *(const bf16x8*)(Kbase + (size_t)(kbn + 16 + c) * 3072 + g * 8);
      nk11 = *(const bf16x8*)(Kbase + (size_t)(kbn + 16 + c) * 3072 + 32 + g * 8);

      // ---- in-lane masked softmax (exp2 domain) ----
      float v0[4], v1[4];
#pragma unroll
      for (int r = 0; r < 4; ++r) {
        v0[r] = (kb + g4 + r <= qc) ? s0[r] : -__builtin_inff();
        v1[r] = (kb + 16 + g4 + r <= qc) ? s1[r] : -__builtin_inff();
      }
      float vm = fmaxf(fmaxf(fmaxf(v0[0], v0[1]), fmaxf(v0[2], v0[3])),
                       fmaxf(fmaxf(v1[0], v1[1]), fmaxf(v1[2], v1[3])));
      vm = fmaxf(vm, __shfl_xor(vm, 16));
      vm = fmaxf(vm, __shfl_xor(vm, 32));

      float mn;
      if (__all(vm - m_c <= 5.0f)) {   // defer-max: P bounded by 2^5
        mn = m_c;
      } else {
        mn = fmaxf(m_c, vm);
        const float al = exp2f(m_c - mn);
        m_c = mn;
        ll_c *= al;
#pragma unroll
        for (int r = 0; r < 4; ++r) {
          const float alr = __shfl(al, g4 + r);
          o[0][r] *= alr; o[1][r] *= alr; o[2][r] *= alr; o[3][r] *= alr;
        }
      }

      float p0[4], p1[4];
#pragma unroll
      for (int r = 0; r < 4; ++r) {
        p0[r] = exp2f(v0[r] - mn);
        p1[r] = exp2f(v1[r] - mn);
      }
      float rs = (p0[0] + p0[1]) + (p0[2] + p0[3]) +
                 (p1[0] + p1[1]) + (p1[2] + p1[3]);
      rs += __shfl_xor(rs, 16);
      rs += __shfl_xor(rs, 32);
      ll_c += rs;

      // write P transposed: pl[w][q local][kv local]
      ushort4 pw;
      pw.x = f2bf(p0[0]); pw.y = f2bf(p0[1]); pw.z = f2bf(p0[2]); pw.w = f2bf(p0[3]);
      *(ushort4*)&pl[w][c][g4] = pw;
      pw.x = f2bf(p1[0]); pw.y = f2bf(p1[1]); pw.z = f2bf(p1[2]); pw.w = f2bf(p1[3]);
      *(ushort4*)&pl[w][c][16 + g4] = pw;

      // P as A-frag: row = q local = c, k = kv local = g*8+j
      const bf16x8 pa = *(const bf16x8*)&pl[w][c][g * 8];
      o[0] = MFMA16(pa, bv0, o[0]);
      o[1] = MFMA16(pa, bv1, o[1]);
      o[2] = MFMA16(pa, bv2, o[2]);
      o[3] = MFMA16(pa, bv3, o[3]);
    }

    const float inv = 1.0f / ll_c;
#pragma unroll
    for (int r = 0; r < 4; ++r) {
      const float invr = __shfl(inv, g4 + r);
      const size_t row = (size_t)(b * 2048 + q0 + g4 + r);
#pragma unroll
      for (int dt = 0; dt < 4; ++dt)
        aout[row * 1024 + h * 64 + dt * 16 + c] = f2bf(o[dt][r] * invr);
    }
  }
}

// ---------------------------------------------------------------------------
extern "C" void kernel_launch(void* const* d_in, const int* in_sizes, int n_in,
                              void* d_out, int out_size, void* d_ws, size_t ws_size,
                              hipStream_t stream) {
  const float* x = (const float*)d_in[0];      // [2,2048,1024]
  const float* wqkv = (const float*)d_in[1];   // [1024,3072]
  const float* wout = (const float*)d_in[2];   // [1024,1024]
  float* out = (float*)d_out;                  // [2,2048,1024] f32

  unsigned short* ws = (unsigned short*)d_ws;
  unsigned short* xb = ws;                                  // 4096*1024
  unsigned short* wqkvT = xb + (size_t)4096 * 1024;         // 3072*1024
  unsigned short* woutT = wqkvT + (size_t)3072 * 1024;      // 1024*1024
  unsigned short* qkv = woutT + (size_t)1024 * 1024;        // 4096*3072
  unsigned short* vT = qkv + (size_t)4096 * 3072;           // 2*1024*2048
  unsigned short* aout = vT + (size_t)2 * 1024 * 2048;      // 4096*1024

  cast_bf16_kernel<<<4096, 256, 0, stream>>>(x, xb, 4096 * 1024 / 4);
  transpose_cast_kernel<<<dim3(96, 32), dim3(32, 8), 0, stream>>>(wqkv, wqkvT, 1024, 3072, 1024);
  transpose_cast_kernel<<<dim3(32, 32), dim3(32, 8), 0, stream>>>(wout, woutT, 1024, 1024, 0);
  gemm128_kernel<1><<<dim3(24, 32), 256, 0, stream>>>(xb, wqkvT, qkv, 4096, 3072, 1024);
  transpose_v_kernel<<<dim3(32, 64, 2), dim3(32, 8), 0, stream>>>(qkv, vT);
  attn_kernel<<<512, 256, 0, stream>>>(qkv, vT, aout);
  gemm128_kernel<0><<<dim3(8, 32), 256, 0, stream>>>(aout, woutT, out, 4096, 1024, 1024);
}